// Round 9
// baseline (388.202 us; speedup 1.0000x reference)
//
#include <hip/hip_runtime.h>
#include <hip/hip_fp16.h>

#define N_NODES 100000
#define N_EDGES 1600000
#define N_BUCKETS 512
#define BUCKET_NODES 196      // 512*196 = 100352 >= N_NODES
#define BKT_BLOCKS 512
#define CAP_E 4096            // raw edges per bucket: mean 3125
#define CAP_C 6144            // padded(8) col slots per bucket: mean ~3920
#define DUMMY N_NODES         // zero feature row (offset DUMMY*32 per chunk)
#define NCHUNK 4              // 64 dims -> 4 chunks of 16 dims (32 B rows)
#define CHUNKB 3276800        // chunk stride: >= (N_NODES+2)*32, 3.125 MB < 4 MB L2

typedef unsigned short u16;
typedef _Float16 f16x8 __attribute__((ext_vector_type(8)));
typedef float f32x4 __attribute__((ext_vector_type(4)));

__device__ __forceinline__ u16 f2h(float f) {
    return __half_as_ushort(__float2half_rn(f));
}

__device__ __forceinline__ void acc8(float* acc, uint4 q) {
    unsigned v[4] = {q.x, q.y, q.z, q.w};
#pragma unroll
    for (int i = 0; i < 4; ++i) {
        __half2 h = *reinterpret_cast<__half2*>(&v[i]);
        float2 f = __half22float2(h);
        acc[2 * i] += f.x;
        acc[2 * i + 1] += f.y;
    }
}

// ---- phase 1: bucket edges into CONTIGUOUS per-bucket runs (R8 form).
//      Blocks >= BKT_BLOCKS instead do the one-time W fragment permute. ----
__global__ __launch_bounds__(256) void k_bucket(const int* __restrict__ src,
                                                const int* __restrict__ dst,
                                                int* __restrict__ btot,
                                                int* __restrict__ ebuf,
                                                const float* __restrict__ W1,
                                                const float* __restrict__ W2,
                                                const float* __restrict__ W3,
                                                u16* __restrict__ Wp) {
    __shared__ int cnt[N_BUCKETS], base_s[N_BUCKETS];
    if (blockIdx.x >= BKT_BLOCKS) {  // fused k_prepw
        int wb = blockIdx.x - BKT_BLOCKS;
        const float* W = wb == 0 ? W1 : (wb == 1 ? W2 : W3);
        u16* o = Wp + wb * 4096;
        for (int f = threadIdx.x; f < 4096; f += 256) {
            int j = f & 7, l16 = (f >> 3) & 15, quad = (f >> 7) & 3;
            int c = (f >> 9) & 1, t = f >> 10;
            o[f] = f2h(W[(quad * 8 + 32 * c + j) * 64 + 4 * l16 + t]);
        }
        return;
    }
    const int CS = N_EDGES / BKT_BLOCKS;  // 3125
    int t = threadIdx.x;
    int beg = blockIdx.x * CS, end = beg + CS;
    for (int i = t; i < N_BUCKETS; i += 256) cnt[i] = 0;
    __syncthreads();
    for (int e = beg + t; e < end; e += 256)
        atomicAdd(&cnt[(unsigned)dst[e] / BUCKET_NODES], 1);
    __syncthreads();
    for (int i = t; i < N_BUCKETS; i += 256) {
        base_s[i] = atomicAdd(&btot[i], cnt[i]);
        cnt[i] = 0;  // reuse as local cursor
    }
    __syncthreads();
    for (int e = beg + t; e < end; e += 256) {
        int d = dst[e], s = src[e];
        int b = (unsigned)d / BUCKET_NODES;
        int l = atomicAdd(&cnt[b], 1);
        ebuf[b * CAP_E + base_s[b] + l] = s | ((d - b * BUCKET_NODES) << 17);
    }
}

// ---- phase 2: per-bucket LDS bin; PAD-8 rows; col = CHUNK-ROW byte offsets
//      (node*32); 16-entry DUMMY guard; fused xs(fp16,chunked) = z*dinv. ----
__global__ __launch_bounds__(512) void k_build(const int* __restrict__ btot,
                                               const int* __restrict__ ebuf,
                                               int* __restrict__ col,
                                               int2* __restrict__ rowinfo,
                                               float* __restrict__ dinv,
                                               const float* __restrict__ z,
                                               u16* __restrict__ xs,
                                               u16* __restrict__ xs_other) {
    __shared__ int deg[BUCKET_NODES];
    __shared__ int cur[BUCKET_NODES];
    __shared__ int wsum[4];
    __shared__ int cls[CAP_C];
    int b = blockIdx.x, t = threadIdx.x;
    int nb = b * BUCKET_NODES;
    int nn = N_NODES - nb;
    if (nn > BUCKET_NODES) nn = BUCKET_NODES;
    int ne = btot[b];
    const int* eb = ebuf + b * CAP_E;

    for (int i = t; i < BUCKET_NODES; i += 512) deg[i] = 0;
    __syncthreads();
    for (int e = t; e < ne; e += 512) atomicAdd(&deg[eb[e] >> 17], 1);
    __syncthreads();

    // pad-to-8 lengths; inclusive wave-shuffle scan over 256 slots (nn<=196)
    int pv = (t < nn) ? ((deg[t] + 7) & ~7) : 0;
    int v = pv;
    int lane = t & 63, wv = t >> 6;
#pragma unroll
    for (int off = 1; off < 64; off <<= 1) {
        int u = __shfl_up(v, off, 64);
        if (lane >= off) v += u;
    }
    if (t < 256 && lane == 63) wsum[wv] = v;
    __syncthreads();
    int total = wsum[0] + wsum[1] + wsum[2] + wsum[3];
    int add = 0;
    for (int i = 0; i < wv && i < 4; ++i) add += wsum[i];
    int incl = v + add;  // inclusive scan value for slot t (t<256)

    int colbase = b * CAP_C;
    if (t < nn) {
        int off0 = incl - pv;
        cur[t] = off0;
        rowinfo[nb + t] = make_int2(colbase + off0, pv);
        dinv[nb + t] = rsqrtf((float)deg[t] + 1.0f);
    }
    __syncthreads();
    for (int i = t; i < total; i += 512) cls[i] = DUMMY << 5;  // pads pre-filled
    __syncthreads();
    for (int e = t; e < ne; e += 512) {
        int pe = eb[e];
        int l = atomicAdd(&cur[pe >> 17], 1);
        cls[l] = (pe & 0x1FFFF) << 5;  // chunk-row byte offset of src row
    }
    __syncthreads();
    for (int i = t; i < total; i += 512) col[colbase + i] = cls[i];
    if (t < 16) col[colbase + total + t] = DUMMY << 5;  // guard for clamped reads

    // fused scale: xs(fp16, chunked layout) = z * dinv for this bucket's rows
    const float4* zz = (const float4*)(z + (size_t)nb * 64);
    for (int i = t; i < nn * 16; i += 512) {
        int nodei = i >> 4, g = i & 15, c = g >> 2, part = g & 3;
        float4 vv = zz[i];
        float dd = rsqrtf((float)deg[nodei] + 1.0f);
        unsigned p0 = (unsigned)f2h(vv.x * dd) | ((unsigned)f2h(vv.y * dd) << 16);
        unsigned p1 = (unsigned)f2h(vv.z * dd) | ((unsigned)f2h(vv.w * dd) << 16);
        *(uint2*)((char*)xs + (size_t)c * CHUNKB + (size_t)(nb + nodei) * 32 +
                  part * 8) = make_uint2(p0, p1);
    }
    if (b == 0 && t < 32) {  // zero dummy rows (4 chunks x 32B) of both buffers
        int tt = t & 15, c = tt >> 2, part = tt & 3;
        char* base = (t < 16) ? (char*)xs : (char*)xs_other;
        *(uint2*)(base + (size_t)c * CHUNKB + (size_t)DUMMY * 32 + part * 8) =
            make_uint2(0, 0);
    }
}

// ---- chunked gather aggregation: gridDim.y = chunk (4 passes of 16 dims).
//      Per pass the gather source is a 3.2 MB L2-RESIDENT slab: the random
//      reads that were fabric misses become L2 hits. Pair-node waves,
//      2 lanes/slot (32B rows), 16-slot main iters + 8-slot tail; col loads
//      nontemporal so the 7MB/pass stream doesn't evict the chunk.
//      reduction: shfl_xor over slot bits {2,4,8,16}; self added after.
//      h[n](chunk c) = fp16( dinv[n]*(sum_row xs_c[s] + xs_c[n]) ). ----
__global__ __launch_bounds__(256) void k_agg(const int2* __restrict__ rowinfo,
                                             const int* __restrict__ col,
                                             const float* __restrict__ dinv,
                                             const u16* __restrict__ xs,
                                             u16* __restrict__ h) {
    const int lane = threadIdx.x & 63;
    const int node = lane >> 5;          // 2 nodes per wave
    const int slot16 = (lane >> 1) & 15; // 16 slots, 2 lanes each
    const int slot8 = (lane >> 1) & 7;
    const int hb = lane & 1;             // which 16B half of the 32B row
    const char* xc = (const char*)xs + (size_t)blockIdx.y * CHUNKB;
    char* hc = (char*)h + (size_t)blockIdx.y * CHUNKB;

    int wave = (blockIdx.x * blockDim.x + threadIdx.x) >> 6;  // 0..49999
    int u0 = __builtin_amdgcn_readfirstlane(wave * 2);
    int2 r0 = rowinfo[u0];
    int2 r1 = rowinfo[u0 + 1];
    int2 rn = node ? r1 : r0;
    int itn = rn.y >> 4;
    int it0 = r0.y >> 4, it1 = r1.y >> 4;
    int itm = it0 > it1 ? it0 : it1;

    // iter-0 + tail cols (clamped/guarded addresses are always valid)
    int cm = __builtin_nontemporal_load(col + rn.x + slot16);
    int tc = __builtin_nontemporal_load(col + rn.x + (itn << 4) + slot8);
    uint4 q = *(const uint4*)(xc + (unsigned)cm + hb * 16);
    uint4 g = *(const uint4*)(xc + (unsigned)tc + hb * 16);
    uint4 s = *(const uint4*)(xc + (size_t)(u0 + node) * 32 + hb * 16);
    float dv = dinv[u0 + node];

    float a[8] = {0.f, 0.f, 0.f, 0.f, 0.f, 0.f, 0.f, 0.f};
    if (0 < itn) acc8(a, q);
    if (((rn.y >> 3) & 1) && !(lane & 16)) acc8(a, g);  // tail once per slot

    // rare path: remaining 16-slot iterations
    for (int rr = 1; rr < itm; ++rr) {
        int c2 = __builtin_nontemporal_load(
            col + rn.x + ((rr < itn ? rr : 0) << 4) + slot16);
        uint4 q2 = *(const uint4*)(xc + (unsigned)c2 + hb * 16);
        if (rr < itn) acc8(a, q2);
    }

    // reduce over slot bits (lane bits 1..4), preserving node(bit5)+half(bit0)
#pragma unroll
    for (int m = 2; m <= 16; m <<= 1) {
#pragma unroll
        for (int j = 0; j < 8; ++j) a[j] += __shfl_xor(a[j], m, 64);
    }
    acc8(a, s);  // self-loop row (identical in all lanes of the group)

    uint4 p;
    u16* pp = (u16*)&p;
#pragma unroll
    for (int j = 0; j < 8; ++j) pp[j] = f2h(a[j] * dv);
    if (slot16 == 0)
        *(uint4*)(hc + (size_t)(u0 + node) * 32 + hb * 16) = p;
}

// ---- MFMA matvec: out = epi( h @ W + b ), 16-row chunks per wave.
//      A fragments read from the CHUNKED h layout; hidden output written
//      chunked (next k_agg's gather source), final output canonical f32. ----
__global__ __launch_bounds__(256) void k_mv(const u16* __restrict__ h,
                                            const u16* __restrict__ Wp,
                                            const float* __restrict__ bias,
                                            const float* __restrict__ dinv,
                                            u16* __restrict__ outh,
                                            float* __restrict__ outf, int hidden) {
    const int lane = threadIdx.x & 63;
    const int quad = lane >> 4;
    const int l16 = lane & 15;
    const char* hb8 = (const char*)h;

    const uint4* wq = (const uint4*)Wp;
    union { uint4 u; f16x8 f; } bfr[4][2];
#pragma unroll
    for (int t = 0; t < 4; ++t)
#pragma unroll
        for (int c = 0; c < 2; ++c)
            bfr[t][c].u = wq[t * 128 + c * 64 + quad * 16 + l16];
    float4 bq = ((const float4*)bias)[l16];
    float bv[4] = {bq.x, bq.y, bq.z, bq.w};

    int wave = (blockIdx.x * blockDim.x + threadIdx.x) >> 6;
    int nwaves = (gridDim.x * blockDim.x) >> 6;
    for (int chunk = wave; chunk < N_NODES / 16; chunk += nwaves) {
        int row0 = chunk * 16;
        // A row l16, dims [quad*8, quad*8+8) -> chunk quad>>1, half quad&1;
        // a1 = dims+32 -> chunk 2+(quad>>1)
        union { uint4 u; f16x8 f; } a0, a1;
        size_t roff = (size_t)(row0 + l16) * 32 + (quad & 1) * 16;
        a0.u = *(const uint4*)(hb8 + (size_t)(quad >> 1) * CHUNKB + roff);
        a1.u = *(const uint4*)(hb8 + (size_t)(2 + (quad >> 1)) * CHUNKB + roff);

        f32x4 acc[4] = {{0.f, 0.f, 0.f, 0.f}, {0.f, 0.f, 0.f, 0.f},
                        {0.f, 0.f, 0.f, 0.f}, {0.f, 0.f, 0.f, 0.f}};
#pragma unroll
        for (int t = 0; t < 4; ++t) {
            acc[t] = __builtin_amdgcn_mfma_f32_16x16x32_f16(a0.f, bfr[t][0].f, acc[t], 0, 0, 0);
            acc[t] = __builtin_amdgcn_mfma_f32_16x16x32_f16(a1.f, bfr[t][1].f, acc[t], 0, 0, 0);
        }
        float dv[4];
#pragma unroll
        for (int r = 0; r < 4; ++r) dv[r] = dinv[row0 + quad * 4 + r];
#pragma unroll
        for (int r = 0; r < 4; ++r) {
            int row = row0 + quad * 4 + r;
            float o[4];
#pragma unroll
            for (int t = 0; t < 4; ++t) o[t] = acc[t][r] + bv[t];
            if (hidden) {
                float dd = dv[r];
#pragma unroll
                for (int t = 0; t < 4; ++t) o[t] = fmaxf(o[t], 0.f) * dd;
                unsigned lo = (unsigned)f2h(o[0]) | ((unsigned)f2h(o[1]) << 16);
                unsigned hi = (unsigned)f2h(o[2]) | ((unsigned)f2h(o[3]) << 16);
                // dims [4*l16,4*l16+4) -> chunk l16>>2, byte (l16&3)*8
                *(uint2*)((char*)outh + (size_t)(l16 >> 2) * CHUNKB +
                          (size_t)row * 32 + (l16 & 3) * 8) = make_uint2(lo, hi);
            } else {
                ((float4*)(outf + (size_t)row * 64))[l16] =
                    make_float4(o[0], o[1], o[2], o[3]);
            }
        }
    }
}

extern "C" void kernel_launch(void* const* d_in, const int* in_sizes, int n_in,
                              void* d_out, int out_size, void* d_ws, size_t ws_size,
                              hipStream_t stream) {
    const float* z  = (const float*)d_in[0];
    const int* src  = (const int*)d_in[1];
    const int* dst  = (const int*)d_in[2];
    const float* W1 = (const float*)d_in[3];
    const float* b1 = (const float*)d_in[4];
    const float* W2 = (const float*)d_in[5];
    const float* b2 = (const float*)d_in[6];
    const float* W3 = (const float*)d_in[7];
    const float* b3 = (const float*)d_in[8];
    float* out = (float*)d_out;

    char* p = (char*)d_ws;
    float* dinv    = (float*)p;  p += (size_t)512 << 10;
    int2*  rowinfo = (int2*)p;   p += (size_t)1 << 20;                   // 800 KB used
    int*   btot    = (int*)p;    p += (size_t)4 << 10;                   // 2 KB used
    int*   ebuf    = (int*)p;    p += (size_t)N_BUCKETS * CAP_E * 4;     // 8 MB
    int*   col     = (int*)p;    p += (size_t)N_BUCKETS * CAP_C * 4;     // 12.6 MB
    u16*   hbuf    = (u16*)p;    p += (size_t)13 << 20;                  // 4xCHUNKB used
    u16*   buf0    = (u16*)p;    p += (size_t)13 << 20;                  // chunked
    u16*   buf1    = (u16*)p;    p += (size_t)13 << 20;                  // chunked
    u16*   wp      = (u16*)p;                                            // 24 KB

    const dim3 gA(12500, NCHUNK);  // 50000 waves x 2 nodes; y = feature chunk
    const int gM = 1563;           // 6252 waves, ~1 chunk each

    // ---- CSR build (512 buckets) + W permute (fused) + fp16 chunked scale ----
    hipMemsetAsync(btot, 0, N_BUCKETS * sizeof(int), stream);
    k_bucket<<<BKT_BLOCKS + 3, 256, 0, stream>>>(src, dst, btot, ebuf, W1, W2, W3, wp);
    k_build<<<N_BUCKETS, 512, 0, stream>>>(btot, ebuf, col, rowinfo, dinv, z, buf0, buf1);

    // ---- 3 layers: agg (4 chunked passes) + mv (MFMA matvec) ----
    k_agg<<<gA, 256, 0, stream>>>(rowinfo, col, dinv, buf0, hbuf);
    k_mv <<<gM, 256, 0, stream>>>(hbuf, wp, b1, dinv, buf1, nullptr, 1);
    k_agg<<<gA, 256, 0, stream>>>(rowinfo, col, dinv, buf1, hbuf);
    k_mv <<<gM, 256, 0, stream>>>(hbuf, wp + 4096, b2, dinv, buf0, nullptr, 1);
    k_agg<<<gA, 256, 0, stream>>>(rowinfo, col, dinv, buf0, hbuf);
    k_mv <<<gM, 256, 0, stream>>>(hbuf, wp + 8192, b3, dinv, nullptr, out, 0);
}

// Round 10
// 250.882 us; speedup vs baseline: 1.5474x; 1.5474x over previous
//
#include <hip/hip_runtime.h>
#include <hip/hip_fp16.h>

#define N_NODES 100000
#define N_EDGES 1600000
#define N_BUCKETS 512
#define BUCKET_NODES 196      // 512*196 = 100352 >= N_NODES
#define BKT_BLOCKS 512
#define CAP_E 4096            // raw edges per bucket: mean 3125
#define CAP_C 6144            // padded(8) col slots per bucket: mean ~3920
#define DUMMY N_NODES         // zero feature row (byte offset DUMMY*128)

typedef unsigned short u16;
typedef _Float16 f16x8 __attribute__((ext_vector_type(8)));
typedef float f32x4 __attribute__((ext_vector_type(4)));
typedef unsigned u32x4 __attribute__((ext_vector_type(4)));

__device__ __forceinline__ u16 f2h(float f) {
    return __half_as_ushort(__float2half_rn(f));
}

__device__ __forceinline__ void acc8v(float* acc, u32x4 q) {
#pragma unroll
    for (int i = 0; i < 4; ++i) {
        unsigned w = q[i];
        __half2 h = *reinterpret_cast<__half2*>(&w);
        float2 f = __half22float2(h);
        acc[2 * i] += f.x;
        acc[2 * i + 1] += f.y;
    }
}

__device__ __forceinline__ void acc8(float* acc, uint4 q) {
    unsigned v[4] = {q.x, q.y, q.z, q.w};
#pragma unroll
    for (int i = 0; i < 4; ++i) {
        __half2 h = *reinterpret_cast<__half2*>(&v[i]);
        float2 f = __half22float2(h);
        acc[2 * i] += f.x;
        acc[2 * i + 1] += f.y;
    }
}

// ---- phase 1: bucket edges into CONTIGUOUS per-bucket runs (R8 form).
//      Blocks >= BKT_BLOCKS instead do the one-time W fragment permute. ----
__global__ __launch_bounds__(256) void k_bucket(const int* __restrict__ src,
                                                const int* __restrict__ dst,
                                                int* __restrict__ btot,
                                                int* __restrict__ ebuf,
                                                const float* __restrict__ W1,
                                                const float* __restrict__ W2,
                                                const float* __restrict__ W3,
                                                u16* __restrict__ Wp) {
    __shared__ int cnt[N_BUCKETS], base_s[N_BUCKETS];
    if (blockIdx.x >= BKT_BLOCKS) {  // fused k_prepw
        int wb = blockIdx.x - BKT_BLOCKS;
        const float* W = wb == 0 ? W1 : (wb == 1 ? W2 : W3);
        u16* o = Wp + wb * 4096;
        for (int f = threadIdx.x; f < 4096; f += 256) {
            int j = f & 7, l16 = (f >> 3) & 15, quad = (f >> 7) & 3;
            int c = (f >> 9) & 1, t = f >> 10;
            o[f] = f2h(W[(quad * 8 + 32 * c + j) * 64 + 4 * l16 + t]);
        }
        return;
    }
    const int CS = N_EDGES / BKT_BLOCKS;  // 3125
    int t = threadIdx.x;
    int beg = blockIdx.x * CS, end = beg + CS;
    for (int i = t; i < N_BUCKETS; i += 256) cnt[i] = 0;
    __syncthreads();
    for (int e = beg + t; e < end; e += 256)
        atomicAdd(&cnt[(unsigned)dst[e] / BUCKET_NODES], 1);
    __syncthreads();
    for (int i = t; i < N_BUCKETS; i += 256) {
        base_s[i] = atomicAdd(&btot[i], cnt[i]);
        cnt[i] = 0;  // reuse as local cursor
    }
    __syncthreads();
    for (int e = beg + t; e < end; e += 256) {
        int d = dst[e], s = src[e];
        int b = (unsigned)d / BUCKET_NODES;
        int l = atomicAdd(&cnt[b], 1);
        ebuf[b * CAP_E + base_s[b] + l] = s | ((d - b * BUCKET_NODES) << 17);
    }
}

// ---- phase 2: per-bucket LDS bin; PAD-8 rows; col = byte offsets; 16-entry
//      DUMMY guard; fused xs(fp16) = z*dinv. 512x512, wave-shuffle scan. ----
__global__ __launch_bounds__(512) void k_build(const int* __restrict__ btot,
                                               const int* __restrict__ ebuf,
                                               int* __restrict__ col,
                                               int2* __restrict__ rowinfo,
                                               float* __restrict__ dinv,
                                               const float* __restrict__ z,
                                               u16* __restrict__ xs,
                                               u16* __restrict__ xs_other) {
    __shared__ int deg[BUCKET_NODES];
    __shared__ int cur[BUCKET_NODES];
    __shared__ int wsum[4];
    __shared__ int cls[CAP_C];
    int b = blockIdx.x, t = threadIdx.x;
    int nb = b * BUCKET_NODES;
    int nn = N_NODES - nb;
    if (nn > BUCKET_NODES) nn = BUCKET_NODES;
    int ne = btot[b];
    const int* eb = ebuf + b * CAP_E;

    for (int i = t; i < BUCKET_NODES; i += 512) deg[i] = 0;
    __syncthreads();
    for (int e = t; e < ne; e += 512) atomicAdd(&deg[eb[e] >> 17], 1);
    __syncthreads();

    // pad-to-8 lengths; inclusive wave-shuffle scan over 256 slots (nn<=196)
    int pv = (t < nn) ? ((deg[t] + 7) & ~7) : 0;
    int v = pv;
    int lane = t & 63, wv = t >> 6;
#pragma unroll
    for (int off = 1; off < 64; off <<= 1) {
        int u = __shfl_up(v, off, 64);
        if (lane >= off) v += u;
    }
    if (t < 256 && lane == 63) wsum[wv] = v;
    __syncthreads();
    int total = wsum[0] + wsum[1] + wsum[2] + wsum[3];
    int add = 0;
    for (int i = 0; i < wv && i < 4; ++i) add += wsum[i];
    int incl = v + add;  // inclusive scan value for slot t (t<256)

    int colbase = b * CAP_C;
    if (t < nn) {
        int off0 = incl - pv;
        cur[t] = off0;
        rowinfo[nb + t] = make_int2(colbase + off0, pv);
        dinv[nb + t] = rsqrtf((float)deg[t] + 1.0f);
    }
    __syncthreads();
    for (int i = t; i < total; i += 512) cls[i] = DUMMY << 7;  // pads pre-filled
    __syncthreads();
    for (int e = t; e < ne; e += 512) {
        int pe = eb[e];
        int l = atomicAdd(&cur[pe >> 17], 1);
        cls[l] = (pe & 0x1FFFF) << 7;  // byte offset of src row
    }
    __syncthreads();
    for (int i = t; i < total; i += 512) col[colbase + i] = cls[i];
    if (t < 16) col[colbase + total + t] = DUMMY << 7;  // guard for clamped reads

    // fused scale: xs(fp16) = z * dinv for this bucket's rows
    const float4* zz = (const float4*)(z + (size_t)nb * 64);
    uint2* xx = (uint2*)(xs + (size_t)nb * 64);
    for (int i = t; i < nn * 16; i += 512) {
        float4 vv = zz[i];
        float dd = rsqrtf((float)deg[i >> 4] + 1.0f);
        unsigned p0 = (unsigned)f2h(vv.x * dd) | ((unsigned)f2h(vv.y * dd) << 16);
        unsigned p1 = (unsigned)f2h(vv.z * dd) | ((unsigned)f2h(vv.w * dd) << 16);
        xx[i] = make_uint2(p0, p1);
    }
    if (b == 0 && t < 8) {  // zero dummy rows of both fp16 feature buffers
        ((uint4*)(xs + (size_t)N_NODES * 64))[t] = make_uint4(0, 0, 0, 0);
        ((uint4*)(xs_other + (size_t)N_NODES * 64))[t] = make_uint4(0, 0, 0, 0);
    }
}

// ---- gather-only aggregation, pad-8 rows, QUAD-node waves.
//      ALL 13 gathers (8 main + 4 tail + 1 combined-self covering 4 rows)
//      issued in ONE indivisible asm block with early-clobber dests and the
//      vmcnt(0) inside. Proven (r8): this is the gather floor — the L3/fabric
//      random-128B service path (~2.2 TB/s) limits, not issue depth (2..13
//      all equal), not occupancy, not footprint (chunking regresses via
//      per-XCD L2 replication, r9).
//      h[n] = fp16( dinv[n]*(sum_{s in row(n)} xs[s] + xs[n]) ). ----
__global__ __launch_bounds__(256, 2) void k_agg(const int2* __restrict__ rowinfo,
                                                const int* __restrict__ col,
                                                const float* __restrict__ dinv,
                                                const u16* __restrict__ xs,
                                                u16* __restrict__ h) {
    const int lane = threadIdx.x & 63;
    const int eighth = lane >> 3;
    const int fh = lane & 7;
    const char* xb = (const char*)xs;
    int wave = (blockIdx.x * blockDim.x + threadIdx.x) >> 6;
    int nwaves = (gridDim.x * blockDim.x) >> 6;

    for (int n0 = wave * 4; n0 < N_NODES; n0 += nwaves * 4) {
        int u0 = __builtin_amdgcn_readfirstlane(n0);  // uniform -> s_loads below
        int2 r0 = rowinfo[u0];
        int2 r1 = rowinfo[u0 + 1];
        int2 r2 = rowinfo[u0 + 2];
        int2 r3 = rowinfo[u0 + 3];
        int it0 = r0.y >> 4, it1 = r1.y >> 4, it2 = r2.y >> 4, it3 = r3.y >> 4;
        int itm = it0 > it1 ? it0 : it1;
        if (it2 > itm) itm = it2;
        if (it3 > itm) itm = it3;

        // iter-0 cols + tail cols (guard slots make every address safe)
        int2 c0 = *(const int2*)(col + r0.x + 2 * eighth);
        int2 c1 = *(const int2*)(col + r1.x + 2 * eighth);
        int2 c2 = *(const int2*)(col + r2.x + 2 * eighth);
        int2 c3 = *(const int2*)(col + r3.x + 2 * eighth);
        int tc0 = col[r0.x + (it0 << 4) + eighth];
        int tc1 = col[r1.x + (it1 << 4) + eighth];
        int tc2 = col[r2.x + (it2 << 4) + eighth];
        int tc3 = col[r3.x + (it3 << 4) + eighth];
        float d0 = dinv[u0];
        float d1 = dinv[u0 + 1];
        float d2 = dinv[u0 + 2];
        float d3 = dinv[u0 + 3];

        const char* A0 = xb + (unsigned)c0.x + fh * 16;
        const char* A1 = xb + (unsigned)c0.y + fh * 16;
        const char* A2 = xb + (unsigned)c1.x + fh * 16;
        const char* A3 = xb + (unsigned)c1.y + fh * 16;
        const char* A4 = xb + (unsigned)c2.x + fh * 16;
        const char* A5 = xb + (unsigned)c2.y + fh * 16;
        const char* A6 = xb + (unsigned)c3.x + fh * 16;
        const char* A7 = xb + (unsigned)c3.y + fh * 16;
        const char* A8 = xb + (unsigned)tc0 + fh * 16;
        const char* A9 = xb + (unsigned)tc1 + fh * 16;
        const char* Aa = xb + (unsigned)tc2 + fh * 16;
        const char* Ab = xb + (unsigned)tc3 + fh * 16;
        const char* Ac = xb + (size_t)(u0 + (eighth & 3)) * 128 + fh * 16;

        u32x4 q0, q1, q2, q3, q4, q5, q6, q7, g0, g1, g2, g3, sf;
        asm volatile(
            "global_load_dwordx4 %0, %13, off\n\t"
            "global_load_dwordx4 %1, %14, off\n\t"
            "global_load_dwordx4 %2, %15, off\n\t"
            "global_load_dwordx4 %3, %16, off\n\t"
            "global_load_dwordx4 %4, %17, off\n\t"
            "global_load_dwordx4 %5, %18, off\n\t"
            "global_load_dwordx4 %6, %19, off\n\t"
            "global_load_dwordx4 %7, %20, off\n\t"
            "global_load_dwordx4 %8, %21, off\n\t"
            "global_load_dwordx4 %9, %22, off\n\t"
            "global_load_dwordx4 %10, %23, off\n\t"
            "global_load_dwordx4 %11, %24, off\n\t"
            "global_load_dwordx4 %12, %25, off\n\t"
            "s_waitcnt vmcnt(0)"
            : "=&v"(q0), "=&v"(q1), "=&v"(q2), "=&v"(q3),
              "=&v"(q4), "=&v"(q5), "=&v"(q6), "=&v"(q7),
              "=&v"(g0), "=&v"(g1), "=&v"(g2), "=&v"(g3), "=&v"(sf)
            : "v"(A0), "v"(A1), "v"(A2), "v"(A3), "v"(A4), "v"(A5),
              "v"(A6), "v"(A7), "v"(A8), "v"(A9), "v"(Aa), "v"(Ab), "v"(Ac)
            : "memory");
        __builtin_amdgcn_sched_barrier(0);  // consumes stay below

        float a0[8] = {0.f, 0.f, 0.f, 0.f, 0.f, 0.f, 0.f, 0.f};
        float a1[8] = {0.f, 0.f, 0.f, 0.f, 0.f, 0.f, 0.f, 0.f};
        float a2[8] = {0.f, 0.f, 0.f, 0.f, 0.f, 0.f, 0.f, 0.f};
        float a3[8] = {0.f, 0.f, 0.f, 0.f, 0.f, 0.f, 0.f, 0.f};
        if (0 < it0) { acc8v(a0, q0); acc8v(a0, q1); }
        if (0 < it1) { acc8v(a1, q2); acc8v(a1, q3); }
        if (0 < it2) { acc8v(a2, q4); acc8v(a2, q5); }
        if (0 < it3) { acc8v(a3, q6); acc8v(a3, q7); }
        if ((r0.y >> 3) & 1) acc8v(a0, g0);
        if ((r1.y >> 3) & 1) acc8v(a1, g1);
        if ((r2.y >> 3) & 1) acc8v(a2, g2);
        if ((r3.y >> 3) & 1) acc8v(a3, g3);
        if (eighth == 0) acc8v(a0, sf);
        if (eighth == 1) acc8v(a1, sf);
        if (eighth == 2) acc8v(a2, sf);
        if (eighth == 3) acc8v(a3, sf);

        // rare path: remaining 16-slot iterations (itm > 1 for ~6% of quads)
        for (int rr = 1; rr < itm; ++rr) {
            int2 e0 = *(const int2*)(col + r0.x + ((rr < it0 ? rr : 0) << 4) + 2 * eighth);
            int2 e1 = *(const int2*)(col + r1.x + ((rr < it1 ? rr : 0) << 4) + 2 * eighth);
            int2 e2 = *(const int2*)(col + r2.x + ((rr < it2 ? rr : 0) << 4) + 2 * eighth);
            int2 e3 = *(const int2*)(col + r3.x + ((rr < it3 ? rr : 0) << 4) + 2 * eighth);
            uint4 p0 = *(const uint4*)(xb + (unsigned)e0.x + fh * 16);
            uint4 p1 = *(const uint4*)(xb + (unsigned)e0.y + fh * 16);
            uint4 p2 = *(const uint4*)(xb + (unsigned)e1.x + fh * 16);
            uint4 p3 = *(const uint4*)(xb + (unsigned)e1.y + fh * 16);
            uint4 p4 = *(const uint4*)(xb + (unsigned)e2.x + fh * 16);
            uint4 p5 = *(const uint4*)(xb + (unsigned)e2.y + fh * 16);
            uint4 p6 = *(const uint4*)(xb + (unsigned)e3.x + fh * 16);
            uint4 p7 = *(const uint4*)(xb + (unsigned)e3.y + fh * 16);
            if (rr < it0) { acc8(a0, p0); acc8(a0, p1); }
            if (rr < it1) { acc8(a1, p2); acc8(a1, p3); }
            if (rr < it2) { acc8(a2, p4); acc8(a2, p5); }
            if (rr < it3) { acc8(a3, p6); acc8(a3, p7); }
        }

#pragma unroll
        for (int m = 8; m <= 32; m <<= 1) {
#pragma unroll
            for (int j = 0; j < 8; ++j) {
                a0[j] += __shfl_xor(a0[j], m, 64);
                a1[j] += __shfl_xor(a1[j], m, 64);
                a2[j] += __shfl_xor(a2[j], m, 64);
                a3[j] += __shfl_xor(a3[j], m, 64);
            }
        }
        uint4 p0, p1, p2, p3;
        u16* pp0 = (u16*)&p0;
        u16* pp1 = (u16*)&p1;
        u16* pp2 = (u16*)&p2;
        u16* pp3 = (u16*)&p3;
#pragma unroll
        for (int j = 0; j < 8; ++j) {
            pp0[j] = f2h(a0[j] * d0);
            pp1[j] = f2h(a1[j] * d1);
            pp2[j] = f2h(a2[j] * d2);
            pp3[j] = f2h(a3[j] * d3);
        }
        if (eighth == 0) ((uint4*)(h + (size_t)u0 * 64))[fh] = p0;
        if (eighth == 1) ((uint4*)(h + (size_t)(u0 + 1) * 64))[fh] = p1;
        if (eighth == 2) ((uint4*)(h + (size_t)(u0 + 2) * 64))[fh] = p2;
        if (eighth == 3) ((uint4*)(h + (size_t)(u0 + 3) * 64))[fh] = p3;
    }
}

// ---- MFMA matvec: out = epi( h @ W + b ), 16-row chunks per wave. ----
__global__ __launch_bounds__(256) void k_mv(const u16* __restrict__ h,
                                            const u16* __restrict__ Wp,
                                            const float* __restrict__ bias,
                                            const float* __restrict__ dinv,
                                            u16* __restrict__ outh,
                                            float* __restrict__ outf, int hidden) {
    const int lane = threadIdx.x & 63;
    const int quad = lane >> 4;
    const int l16 = lane & 15;

    const uint4* wq = (const uint4*)Wp;
    union { uint4 u; f16x8 f; } bfr[4][2];
#pragma unroll
    for (int t = 0; t < 4; ++t)
#pragma unroll
        for (int c = 0; c < 2; ++c)
            bfr[t][c].u = wq[t * 128 + c * 64 + quad * 16 + l16];
    float4 bq = ((const float4*)bias)[l16];
    float bv[4] = {bq.x, bq.y, bq.z, bq.w};

    int wave = (blockIdx.x * blockDim.x + threadIdx.x) >> 6;
    int nwaves = (gridDim.x * blockDim.x) >> 6;
    for (int chunk = wave; chunk < N_NODES / 16; chunk += nwaves) {
        int row0 = chunk * 16;
        const u16* hb = h + (size_t)row0 * 64;
        union { uint4 u; f16x8 f; } a0, a1;
        a0.u = *(const uint4*)(hb + l16 * 64 + quad * 8);
        a1.u = *(const uint4*)(hb + l16 * 64 + quad * 8 + 32);

        f32x4 acc[4] = {{0.f, 0.f, 0.f, 0.f}, {0.f, 0.f, 0.f, 0.f},
                        {0.f, 0.f, 0.f, 0.f}, {0.f, 0.f, 0.f, 0.f}};
#pragma unroll
        for (int t = 0; t < 4; ++t) {
            acc[t] = __builtin_amdgcn_mfma_f32_16x16x32_f16(a0.f, bfr[t][0].f, acc[t], 0, 0, 0);
            acc[t] = __builtin_amdgcn_mfma_f32_16x16x32_f16(a1.f, bfr[t][1].f, acc[t], 0, 0, 0);
        }
        float dv[4];
#pragma unroll
        for (int r = 0; r < 4; ++r) dv[r] = dinv[row0 + quad * 4 + r];
#pragma unroll
        for (int r = 0; r < 4; ++r) {
            int row = row0 + quad * 4 + r;
            float o[4];
#pragma unroll
            for (int t = 0; t < 4; ++t) o[t] = acc[t][r] + bv[t];
            if (hidden) {
                float dd = dv[r];
#pragma unroll
                for (int t = 0; t < 4; ++t) o[t] = fmaxf(o[t], 0.f) * dd;
                unsigned lo = (unsigned)f2h(o[0]) | ((unsigned)f2h(o[1]) << 16);
                unsigned hi = (unsigned)f2h(o[2]) | ((unsigned)f2h(o[3]) << 16);
                ((uint2*)(outh + (size_t)row * 64))[l16] = make_uint2(lo, hi);
            } else {
                ((float4*)(outf + (size_t)row * 64))[l16] =
                    make_float4(o[0], o[1], o[2], o[3]);
            }
        }
    }
}

extern "C" void kernel_launch(void* const* d_in, const int* in_sizes, int n_in,
                              void* d_out, int out_size, void* d_ws, size_t ws_size,
                              hipStream_t stream) {
    const float* z  = (const float*)d_in[0];
    const int* src  = (const int*)d_in[1];
    const int* dst  = (const int*)d_in[2];
    const float* W1 = (const float*)d_in[3];
    const float* b1 = (const float*)d_in[4];
    const float* W2 = (const float*)d_in[5];
    const float* b2 = (const float*)d_in[6];
    const float* W3 = (const float*)d_in[7];
    const float* b3 = (const float*)d_in[8];
    float* out = (float*)d_out;

    char* p = (char*)d_ws;
    float* dinv    = (float*)p;  p += (size_t)512 << 10;
    int2*  rowinfo = (int2*)p;   p += (size_t)1 << 20;                   // 800 KB used
    int*   btot    = (int*)p;    p += (size_t)4 << 10;                   // 2 KB used
    int*   ebuf    = (int*)p;    p += (size_t)N_BUCKETS * CAP_E * 4;     // 8 MB
    int*   col     = (int*)p;    p += (size_t)N_BUCKETS * CAP_C * 4;     // 12.6 MB
    u16*   hbuf    = (u16*)p;    p += (size_t)13 << 20;                  // 12.8 MB used
    u16*   buf0    = (u16*)p;    p += (size_t)13 << 20;                  // +dummy row
    u16*   buf1    = (u16*)p;    p += (size_t)13 << 20;                  // +dummy row
    u16*   wp      = (u16*)p;                                            // 24 KB

    const int gA = 6250;  // 25000 waves: exactly 1 quad per wave
    const int gM = 1563;  // 6252 waves, ~1 chunk each

    // ---- CSR build (512 buckets) + W permute (fused) + fp16 scale ----
    hipMemsetAsync(btot, 0, N_BUCKETS * sizeof(int), stream);
    k_bucket<<<BKT_BLOCKS + 3, 256, 0, stream>>>(src, dst, btot, ebuf, W1, W2, W3, wp);
    k_build<<<N_BUCKETS, 512, 0, stream>>>(btot, ebuf, col, rowinfo, dinv, z, buf0, buf1);

    // ---- 3 layers: agg (gather) + mv (MFMA matvec) ----
    k_agg<<<gA, 256, 0, stream>>>(rowinfo, col, dinv, buf0, hbuf);
    k_mv <<<gM, 256, 0, stream>>>(hbuf, wp, b1, dinv, buf1, nullptr, 1);
    k_agg<<<gA, 256, 0, stream>>>(rowinfo, col, dinv, buf1, hbuf);
    k_mv <<<gM, 256, 0, stream>>>(hbuf, wp + 4096, b2, dinv, buf0, nullptr, 1);
    k_agg<<<gA, 256, 0, stream>>>(rowinfo, col, dinv, buf0, hbuf);
    k_mv <<<gM, 256, 0, stream>>>(hbuf, wp + 8192, b3, dinv, nullptr, out, 0);
}